// Round 4
// baseline (300.709 us; speedup 1.0000x reference)
//
#include <hip/hip_runtime.h>

// GraphSAGE: 2x SAGEConv(mean) + Linear + softmax.
// Pipeline (5 dispatches): memset(gtail) ->
//   bucket_prep (phase-A LDS bucket-sort of edges | cvt x->bf16 | pack W frags)
//   -> fill_csr (phase-B: per-bucket CSR build GROUPED BY SRC RANGE, 2-pass)
//   -> fused_l1 (range-phased gather-mean + dual MFMA GEMM + relu -> h0 bf16)
//   -> fused_l2 (range-phased gather + dual GEMM + relu + out-proj + softmax).
//
// This round: SRC-RANGE-PHASED GATHER (column slicing of round 3 reverted).
// R3 evidence: FETCH=115MB ~= compulsory per-XCD fills (8 x 12.8MB table), but
// random 64B accesses ran the L2<-L3 fill path at only 2TB/s -> 64us. Full
// 256B row fetches are the efficient regime; the remaining waste in R2 was
// CAPACITY misses (12.8MB table vs 4MB/XCD L2 -> 31% hit). Fix: group each
// node's neighbor list by src range (4 ranges x 16384 nodes ~= 4.2MB table
// slice); gather loops ranges OUTERMOST with per-node f32 accumulators in
// registers (a[4][8], node loop fully unrolled -> no scratch). All ~780
// blocks are co-resident -> GPU sweeps ranges roughly in phase -> active
// slice is L2-resident; misses -> compulsory floor at 256B granularity.
// Worst case (total drift) == round-2 behavior: downside bounded.
// Neighbor order within a node is permuted (f32 sum, tol 1e-3: safe).
// Row loads guarded by segment length (kills R2's clamped duplicate loads).
//
// CSR build: bucket = dst>>8 (256-node ranges). Phase A: per-block LDS
// histogram + scan + ~196 global atomics reserving per-(XCD,bucket) segments
// (b&7 XCD heuristic -> single-XCD lines), LDS-sorted dump. Phase B: one
// block per bucket, two passes over its 8 segments: count per (node,src-range)
// -> prefix offsets + packed cnt4 (4 x u8) -> LDS-atomic placement, coalesced
// 32KB tile dump. No global atomics.
//
// Dual GEMM as one K=256 MFMA GEMM: A_cat=[agg|root] bf16, W_cat=[Wl;Wr] packed.
// mfma_f32_16x16x32_bf16: A[m=lane&15][k=(lane>>4)*8+j]; B[k][n=lane&15];
// C: col=lane&15, row=(lane>>4)*4+reg (m89/m91-verified layouts).
// Zero barriers in the fused kernels (wave-private LDS tiles, DS wave-ordered).

#define CAP 64
#define NBK 256      // bucket table stride (max buckets; N<=65536)
#define EPB 2048     // edges per phase-A block (8 per thread)
#define BCAP8 768    // per-(XCD,bucket) segment capacity (mean ~510, ~11 sigma)
#define ASTR 136     // LDS A-tile row stride in ushorts (272B = 17x16B)
#define NR 4         // src ranges for L2 phasing
#define RSH 14       // range = src >> 14  (16384-node ranges, ~4.2MB bf16 each)

typedef __attribute__((ext_vector_type(8))) short bf16x8;
typedef __attribute__((ext_vector_type(4))) float f32x4;

__device__ __forceinline__ unsigned short bf16_rtne(float f) {
    unsigned u = __float_as_uint(f);
    u += 0x7FFFu + ((u >> 16) & 1u);
    return (unsigned short)(u >> 16);
}

__device__ __forceinline__ unsigned pack2(float lo, float hi) {
    return (unsigned)bf16_rtne(lo) | ((unsigned)bf16_rtne(hi) << 16);
}

__device__ __forceinline__ void pack_w_body(const float* __restrict__ Wl,
                                            const float* __restrict__ Wr,
                                            unsigned short* __restrict__ Wp, int i) {
    int j = i & 7;
    int l = (i >> 3) & 63;
    int ntile = (i >> 9) & 7;
    int kstep = i >> 12;
    int k = kstep * 32 + (l >> 4) * 8 + j;
    int n = ntile * 16 + (l & 15);
    float v = (k < 128) ? Wl[k * 128 + n] : Wr[(k - 128) * 128 + n];
    Wp[i] = bf16_rtne(v);
}

// Fused dispatch 1: [phase-A bucket scatter | cvt x->bf16 | pack Wp1/Wp2/Wpo].
__global__ __launch_bounds__(256) void bucket_prep_kernel(
        const int* __restrict__ src, const int* __restrict__ dst,
        unsigned int* __restrict__ gtail, unsigned int* __restrict__ gbuf,
        int E, int aBlocks,
        const float* __restrict__ x, unsigned short* __restrict__ xb, int n4, int cvtBlocks,
        const float* __restrict__ Wl0, const float* __restrict__ Wr0,
        unsigned short* __restrict__ Wp1,
        const float* __restrict__ Wl1, const float* __restrict__ Wr1,
        unsigned short* __restrict__ Wp2,
        const float* __restrict__ Wout, unsigned short* __restrict__ Wpo) {
    int b = blockIdx.x;
    if (b < aBlocks) {
        __shared__ unsigned int hist[NBK];
        __shared__ unsigned int pref[NBK + 1];
        __shared__ int baseS[NBK];
        __shared__ unsigned int scat[EPB];
        __shared__ unsigned char scatb[EPB];
        int tid = (int)threadIdx.x;
        int xcd = b & 7;   // XCD heuristic: same (b&7) -> same XCD L2 for segment writes
        hist[tid] = 0u;
        __syncthreads();

        int e0 = b * EPB + tid * 8;
        int dd[8], ss[8], bb[8];
        unsigned rr[8];
        bool vld[8];
        if (e0 + 7 < E) {
            int4 d0 = *(const int4*)(dst + e0);
            int4 d1 = *(const int4*)(dst + e0 + 4);
            int4 s0 = *(const int4*)(src + e0);
            int4 s1 = *(const int4*)(src + e0 + 4);
            dd[0] = d0.x; dd[1] = d0.y; dd[2] = d0.z; dd[3] = d0.w;
            dd[4] = d1.x; dd[5] = d1.y; dd[6] = d1.z; dd[7] = d1.w;
            ss[0] = s0.x; ss[1] = s0.y; ss[2] = s0.z; ss[3] = s0.w;
            ss[4] = s1.x; ss[5] = s1.y; ss[6] = s1.z; ss[7] = s1.w;
#pragma unroll
            for (int u = 0; u < 8; ++u) vld[u] = true;
        } else {
#pragma unroll
            for (int u = 0; u < 8; ++u) {
                int e = e0 + u;
                vld[u] = (e < E);
                dd[u] = vld[u] ? dst[e] : 0;
                ss[u] = vld[u] ? src[e] : 0;
            }
        }
#pragma unroll
        for (int u = 0; u < 8; ++u) {
            bb[u] = dd[u] >> 8;
            rr[u] = vld[u] ? atomicAdd(&hist[bb[u]], 1u) : 0u;
        }
        __syncthreads();
        // exclusive prefix over hist: pref[i] = sum hist[0..i-1] (Hillis-Steele)
        pref[tid + 1] = hist[tid];
        if (tid == 0) pref[0] = 0u;
        __syncthreads();
        for (int off = 1; off < NBK; off <<= 1) {
            unsigned add = (tid + 1 > off) ? pref[tid + 1 - off] : 0u;
            __syncthreads();
            pref[tid + 1] += add;
            __syncthreads();
        }
        // reserve per-(XCD,bucket) segment space: ~196 atomics per block
        {
            unsigned h = hist[tid];
            unsigned gb0 = (h != 0u) ? atomicAdd(&gtail[xcd * NBK + tid], h) : 0u;
            baseS[tid] = (int)((unsigned)(xcd * NBK + tid) * BCAP8 + gb0) - (int)pref[tid];
        }
        __syncthreads();
        // local bucket-sort into LDS
#pragma unroll
        for (int u = 0; u < 8; ++u) {
            if (vld[u]) {
                unsigned idx = pref[bb[u]] + rr[u];
                scat[idx] = ((unsigned)dd[u] << 16) | (unsigned)(ss[u] & 0xFFFF);
                scatb[idx] = (unsigned char)bb[u];
            }
        }
        __syncthreads();
        // dump: contiguous run per bucket -> coalesced-ish, single-XCD lines
        unsigned tot = pref[NBK];
        for (unsigned i = (unsigned)tid; i < tot; i += 256u) {
            int bk = (int)scatb[i];
            int gi = baseS[bk] + (int)i;
            unsigned segBase = (unsigned)(xcd * NBK + bk) * BCAP8;
            if ((unsigned)gi - segBase < BCAP8) gbuf[gi] = scat[i];
        }
    } else if (b < aBlocks + cvtBlocks) {
        int i = (b - aBlocks) * 256 + (int)threadIdx.x;
        if (i < n4) {
            float4 v = ((const float4*)x)[i];
            ushort4 o;
            o.x = bf16_rtne(v.x); o.y = bf16_rtne(v.y);
            o.z = bf16_rtne(v.z); o.w = bf16_rtne(v.w);
            ((ushort4*)xb)[i] = o;
        }
    } else if (b < aBlocks + cvtBlocks + 128) {
        pack_w_body(Wl0, Wr0, Wp1, (b - aBlocks - cvtBlocks) * 256 + (int)threadIdx.x);
    } else if (b < aBlocks + cvtBlocks + 256) {
        pack_w_body(Wl1, Wr1, Wp2, (b - aBlocks - cvtBlocks - 128) * 256 + (int)threadIdx.x);
    } else {
        int i = (b - aBlocks - cvtBlocks - 256) * 256 + (int)threadIdx.x;   // 32 blocks
        int j = i & 7;
        int l = (i >> 3) & 63;
        int nt = (i >> 9) & 3;
        int ks = i >> 11;
        int k = ks * 32 + (l >> 4) * 8 + j;
        int n = nt * 16 + (l & 15);
        Wpo[i] = bf16_rtne(Wout[k * 64 + n]);
    }
}

// Phase B: one block per 256-node bucket, two passes over its 8 XCD segments.
// Pass 1 counts per (node, src-range); per-node prefix -> segment offsets +
// packed cnt4 (4 x u8). Pass 2 places edges grouped by range via LDS atomics.
// Coalesced 32KB csr tile dump. No global atomics.
__global__ __launch_bounds__(256) void fill_csr_kernel(
        const unsigned int* __restrict__ gtail, const unsigned int* __restrict__ gbuf,
        unsigned int* __restrict__ cnt4, unsigned short* __restrict__ csr, int N) {
    __shared__ unsigned int cntR[256 * NR];   // 4 KB
    __shared__ unsigned int offR[256 * NR];   // 4 KB
    __shared__ unsigned short stage[256 * CAP];   // 32 KB; garbage beyond deg never read
    int b = blockIdx.x;
    int tid = (int)threadIdx.x;
#pragma unroll
    for (int r = 0; r < NR; ++r) cntR[r * 256 + tid] = 0u;
    __syncthreads();
    // pass 1: count per (node, range)
#pragma unroll 1
    for (int xcd = 0; xcd < 8; ++xcd) {
        unsigned nE = gtail[xcd * NBK + b];
        if (nE > BCAP8) nE = BCAP8;
        const unsigned int* g = gbuf + (size_t)(xcd * NBK + b) * BCAP8;
        for (unsigned i = (unsigned)tid; i < nE; i += 256u) {
            unsigned pk = g[i];
            int dl = (int)((pk >> 16) & 255u);
            int rg = (int)((pk & 0xFFFFu) >> RSH);
            atomicAdd(&cntR[dl * NR + rg], 1u);
        }
    }
    __syncthreads();
    // per-node offsets + packed counts; reset counters for pass 2
    {
        unsigned c0 = cntR[tid * NR + 0], c1 = cntR[tid * NR + 1];
        unsigned c2 = cntR[tid * NR + 2], c3 = cntR[tid * NR + 3];
        offR[tid * NR + 0] = 0u;
        offR[tid * NR + 1] = c0;
        offR[tid * NR + 2] = c0 + c1;
        offR[tid * NR + 3] = c0 + c1 + c2;
        int node = b * 256 + tid;
        if (node < N)
            cnt4[node] = min(c0, 255u) | (min(c1, 255u) << 8) |
                         (min(c2, 255u) << 16) | (min(c3, 255u) << 24);
        cntR[tid * NR + 0] = 0u; cntR[tid * NR + 1] = 0u;
        cntR[tid * NR + 2] = 0u; cntR[tid * NR + 3] = 0u;
    }
    __syncthreads();
    // pass 2: place (grouped by range within each node's CAP row)
#pragma unroll 1
    for (int xcd = 0; xcd < 8; ++xcd) {
        unsigned nE = gtail[xcd * NBK + b];
        if (nE > BCAP8) nE = BCAP8;
        const unsigned int* g = gbuf + (size_t)(xcd * NBK + b) * BCAP8;
        for (unsigned i = (unsigned)tid; i < nE; i += 256u) {
            unsigned pk = g[i];
            int dl = (int)((pk >> 16) & 255u);
            int rg = (int)((pk & 0xFFFFu) >> RSH);
            unsigned p = atomicAdd(&cntR[dl * NR + rg], 1u) + offR[dl * NR + rg];
            if (p < CAP) stage[dl * CAP + p] = (unsigned short)(pk & 0xFFFFu);
        }
    }
    __syncthreads();
    const uint4* s4 = (const uint4*)stage;
    uint4* g4 = (uint4*)(csr + (size_t)b * (256 * CAP));
    for (int i = tid; i < (256 * CAP) / 8; i += 256) g4[i] = s4[i];
}

// Range-phased per-wave gather+mean into the wave's LDS A-tile.
// Range loop OUTERMOST: all co-resident blocks (whole grid fits the GPU)
// sweep src ranges roughly in phase -> the active ~4.2MB table slice is
// per-XCD L2-resident; misses approach the compulsory fill floor while
// keeping full 256B row fetches (the efficient fabric regime, per R3).
// Per-node accumulators a[4][8] live in registers (node loop fully unrolled).
// Row loads guarded by segment length: no clamped duplicate-row traffic.
__device__ __forceinline__ void gather_mean_lds(
        const uint4* __restrict__ h4,          // bf16 table, one row = 16 uint4
        const unsigned* __restrict__ cnt4,     // packed per-range degrees (4 x u8)
        const unsigned short* __restrict__ csr, unsigned short* __restrict__ sAw,
        int m0, int lane, int N) {
    int qw = lane >> 4;      // quarter-wave 0..3
    int ql = lane & 15;
    float a[4][8];
#pragma unroll
    for (int i = 0; i < 4; ++i)
#pragma unroll
        for (int u = 0; u < 8; ++u) a[i][u] = 0.f;
    unsigned pc[4];
    int s0[4];
#pragma unroll
    for (int i = 0; i < 4; ++i) {
        int node = m0 + qw * 4 + i;
        pc[i] = (node < N) ? cnt4[node] : 0u;
        s0[i] = node * CAP;
    }
#pragma unroll 1
    for (int r = 0; r < NR; ++r) {
#pragma unroll
        for (int i = 0; i < 4; ++i) {      // fully unrolled: a[i] stays in VGPRs
            unsigned c = pc[i];
            int prefv = 0;
#pragma unroll
            for (int q = 0; q < NR; ++q)
                if (q < r) prefv += (int)((c >> (8 * q)) & 255u);
            int cr = (int)((c >> (8 * r)) & 255u);
            int st = min(prefv, CAP);
            int en = min(prefv + cr, CAP);
            int base0 = s0[i];
#pragma unroll 1
            for (int base = st; base < en; base += 16) {
                int nc = min(en - base, 16);
                int e = min(base0 + base + ql, base0 + en - 1);
                int idx = csr[e];
#pragma unroll 1
                for (int j = 0; j < nc; j += 8) {
                    uint4 v[8];
                    bool ok[8];
#pragma unroll
                    for (int u = 0; u < 8; ++u) {
                        ok[u] = (j + u < nc);      // uniform per 16-lane group
                        if (ok[u]) {
                            int sidx = __shfl(idx, j + u, 16);
                            v[u] = h4[(size_t)sidx * 16 + ql];
                        }
                    }
#pragma unroll
                    for (int u = 0; u < 8; ++u) {
                        if (ok[u]) {
                            a[i][0] += __uint_as_float(v[u].x << 16);
                            a[i][1] += __uint_as_float(v[u].x & 0xFFFF0000u);
                            a[i][2] += __uint_as_float(v[u].y << 16);
                            a[i][3] += __uint_as_float(v[u].y & 0xFFFF0000u);
                            a[i][4] += __uint_as_float(v[u].z << 16);
                            a[i][5] += __uint_as_float(v[u].z & 0xFFFF0000u);
                            a[i][6] += __uint_as_float(v[u].w << 16);
                            a[i][7] += __uint_as_float(v[u].w & 0xFFFF0000u);
                        }
                    }
                }
            }
        }
    }
#pragma unroll
    for (int i = 0; i < 4; ++i) {
        unsigned c = pc[i];
        int tot = (int)((c & 255u) + ((c >> 8) & 255u) +
                        ((c >> 16) & 255u) + ((c >> 24) & 255u));
        int deg = min(tot, CAP);
        float inv = 1.0f / (float)max(deg, 1);
        int nl = qw * 4 + i;
        uint4 o;
        o.x = pack2(a[i][0] * inv, a[i][1] * inv);
        o.y = pack2(a[i][2] * inv, a[i][3] * inv);
        o.z = pack2(a[i][4] * inv, a[i][5] * inv);
        o.w = pack2(a[i][6] * inv, a[i][7] * inv);
        *(uint4*)(sAw + nl * ASTR + ql * 8) = o;   // 272B row -> bank-floor reads
    }
}

// MFMA core: wave computes 16 nodes x 128 cols, K=256 ([aggLDS|rootGlobal]).
__device__ __forceinline__ void mfma_dual_gemm_lds(
        const unsigned short* __restrict__ sAw, const unsigned short* __restrict__ rootb,
        const unsigned short* __restrict__ Wp, int rowc, int quad, int c, int lane,
        f32x4 acc[8]) {
#pragma unroll
    for (int t = 0; t < 8; ++t) acc[t] = (f32x4){0.f, 0.f, 0.f, 0.f};
    for (int ks = 0; ks < 8; ++ks) {
        bf16x8 a;
        if (ks < 4) a = *(const bf16x8*)(sAw + c * ASTR + ks * 32 + quad * 8);
        else        a = *(const bf16x8*)(rootb + (size_t)rowc * 128 + (ks & 3) * 32 + quad * 8);
#pragma unroll
        for (int t = 0; t < 8; ++t) {
            bf16x8 bf = *(const bf16x8*)(Wp + ((size_t)(ks * 8 + t) * 64 + lane) * 8);
            acc[t] = __builtin_amdgcn_mfma_f32_16x16x32_bf16(a, bf, acc[t], 0, 0, 0);
        }
    }
}

// Layer 1: h0 = relu(mean_agg(x)@Wl + x@Wr + b) -> bf16 store.
// Gather, GEMM, and the h0 repack all stay on the wave's own LDS tile:
// no barriers (DS ops wave-ordered). h0 stored as coalesced 256B rows.
__global__ __launch_bounds__(256) void fused_l1_kernel(
        const unsigned short* __restrict__ hb, const unsigned* __restrict__ cnt4,
        const unsigned short* __restrict__ csr, const unsigned short* __restrict__ Wp,
        const float* __restrict__ b, unsigned short* __restrict__ houtb, int N) {
    __shared__ unsigned short sA[4][16 * ASTR];   // 17.4 KB
    int lane = threadIdx.x & 63;
    int wv = threadIdx.x >> 6;
    int m0 = blockIdx.x * 64 + wv * 16;
    gather_mean_lds((const uint4*)hb, cnt4, csr, &sA[wv][0], m0, lane, N);
    int quad = lane >> 4;
    int c = lane & 15;
    int rowc = min(m0 + c, N - 1);
    f32x4 acc[8];
    mfma_dual_gemm_lds(&sA[wv][0], hb, Wp, rowc, quad, c, lane, acc);
    // relu+bias -> sA (overwrites A-tile; wave-private, DS wave-ordered)
#pragma unroll
    for (int t = 0; t < 8; ++t) {
        int col = t * 16 + c;
        float bias = b[col];
#pragma unroll
        for (int r = 0; r < 4; ++r) {
            sA[wv][(quad * 4 + r) * ASTR + col] = bf16_rtne(fmaxf(acc[t][r] + bias, 0.f));
        }
    }
    // coalesced store: quarter-wave ql covers 16B -> 256B per row per instr
    {
        int qw = lane >> 4, ql = lane & 15;
#pragma unroll
        for (int i = 0; i < 4; ++i) {
            int nl = qw * 4 + i;
            int node = m0 + nl;
            if (node < N) {
                uint4 row = *(const uint4*)(&sA[wv][nl * ASTR + ql * 8]);
                *(uint4*)(houtb + (size_t)node * 128 + ql * 8) = row;
            }
        }
    }
}

// Layer 2 + out-projection + softmax. h1 tile staged back into the same LDS
// A-tile (stride 136 -> conflict-floor reads in the out-proj too). No barriers.
__global__ __launch_bounds__(256) void fused_l2_kernel(
        const unsigned short* __restrict__ hb, const unsigned* __restrict__ cnt4,
        const unsigned short* __restrict__ csr, const unsigned short* __restrict__ Wp,
        const float* __restrict__ b,
        const unsigned short* __restrict__ Wpo, const float* __restrict__ bout,
        float* __restrict__ out, int N) {
    __shared__ unsigned short sA[4][16 * ASTR];   // 17.4 KB, reused for h1 tile
    int lane = threadIdx.x & 63;
    int wv = threadIdx.x >> 6;
    int m0 = blockIdx.x * 64 + wv * 16;
    gather_mean_lds((const uint4*)hb, cnt4, csr, &sA[wv][0], m0, lane, N);
    int quad = lane >> 4;
    int c = lane & 15;
    int rowc = min(m0 + c, N - 1);
    f32x4 acc[8];
    mfma_dual_gemm_lds(&sA[wv][0], hb, Wp, rowc, quad, c, lane, acc);
    // relu -> h1 tile in LDS (wave-private; DS ops are wave-ordered, no barrier)
#pragma unroll
    for (int t = 0; t < 8; ++t) {
        int col = t * 16 + c;
        float bias = b[col];
#pragma unroll
        for (int r = 0; r < 4; ++r) {
            sA[wv][(quad * 4 + r) * ASTR + col] = bf16_rtne(fmaxf(acc[t][r] + bias, 0.f));
        }
    }

    // out = h1 @ Wout : K=128 (4 ksteps), N=64 (4 ntiles) -> 16 MFMAs.
    f32x4 acc2[4];
#pragma unroll
    for (int nt = 0; nt < 4; ++nt) acc2[nt] = (f32x4){0.f, 0.f, 0.f, 0.f};
#pragma unroll
    for (int ks = 0; ks < 4; ++ks) {
        bf16x8 a = *(const bf16x8*)&sA[wv][c * ASTR + ks * 32 + quad * 8];
#pragma unroll
        for (int nt = 0; nt < 4; ++nt) {
            bf16x8 bf = *(const bf16x8*)(Wpo + ((size_t)(ks * 4 + nt) * 64 + lane) * 8);
            acc2[nt] = __builtin_amdgcn_mfma_f32_16x16x32_bf16(a, bf, acc2[nt], 0, 0, 0);
        }
    }

    // softmax: row m=quad*4+r lives in a 16-lane group x 4 regs (nt).
    float bo[4];
#pragma unroll
    for (int nt = 0; nt < 4; ++nt) bo[nt] = bout[nt * 16 + c];
#pragma unroll
    for (int r = 0; r < 4; ++r) {
        float v[4];
#pragma unroll
        for (int nt = 0; nt < 4; ++nt) v[nt] = acc2[nt][r] + bo[nt];
        float m = fmaxf(fmaxf(v[0], v[1]), fmaxf(v[2], v[3]));
#pragma unroll
        for (int ofs = 1; ofs < 16; ofs <<= 1) m = fmaxf(m, __shfl_xor(m, ofs, 64));
        float e[4];
        float s = 0.f;
#pragma unroll
        for (int nt = 0; nt < 4; ++nt) { e[nt] = __expf(v[nt] - m); s += e[nt]; }
#pragma unroll
        for (int ofs = 1; ofs < 16; ofs <<= 1) s += __shfl_xor(s, ofs, 64);
        float inv = 1.0f / s;
        int node = m0 + quad * 4 + r;
        if (node < N) {
#pragma unroll
            for (int nt = 0; nt < 4; ++nt)
                out[(size_t)node * 64 + nt * 16 + c] = e[nt] * inv;
        }
    }
}

extern "C" void kernel_launch(void* const* d_in, const int* in_sizes, int n_in,
                              void* d_out, int out_size, void* d_ws, size_t ws_size,
                              hipStream_t stream) {
    const float* x    = (const float*)d_in[0];
    const int*   ei   = (const int*)d_in[1];
    const float* Wl0  = (const float*)d_in[2];
    const float* Wr0  = (const float*)d_in[3];
    const float* b0   = (const float*)d_in[4];
    const float* Wl1  = (const float*)d_in[5];
    const float* Wr1  = (const float*)d_in[6];
    const float* b1   = (const float*)d_in[7];
    const float* Wout = (const float*)d_in[8];
    const float* bout = (const float*)d_in[9];

    int N = in_sizes[0] / 128;
    int E = in_sizes[1] / 2;
    const int* src = ei;
    const int* dst = ei + E;
    int nb = (N + 255) >> 8;             // node buckets (256 nodes each)

    char* p = (char*)d_ws;
    auto alloc = [&](size_t bytes) -> char* {
        char* r = p;
        p += (bytes + 255) & ~(size_t)255;
        return r;
    };
    unsigned int*   gtail = (unsigned int*)alloc((size_t)8 * NBK * 4);
    unsigned int*   gbuf  = (unsigned int*)alloc((size_t)8 * NBK * BCAP8 * 4);
    unsigned int*   cnt4  = (unsigned int*)alloc((size_t)N * 4);
    unsigned short* csr   = (unsigned short*)alloc((size_t)nb * 256 * CAP * 2);
    unsigned short* xb    = (unsigned short*)alloc((size_t)N * 128 * 2);
    unsigned short* h0b   = (unsigned short*)alloc((size_t)N * 128 * 2);
    unsigned short* Wp1   = (unsigned short*)alloc((size_t)32768 * 2);
    unsigned short* Wp2   = (unsigned short*)alloc((size_t)32768 * 2);
    unsigned short* Wpo   = (unsigned short*)alloc((size_t)8192 * 2);

    hipMemsetAsync(gtail, 0, (size_t)8 * NBK * 4, stream);

    int n4 = N * 128 / 4;
    int cvtBlocks = (n4 + 255) / 256;
    int aBlocks = (E + EPB - 1) / EPB;
    bucket_prep_kernel<<<aBlocks + cvtBlocks + 256 + 32, 256, 0, stream>>>(
        src, dst, gtail, gbuf, E, aBlocks,
        x, xb, n4, cvtBlocks, Wl0, Wr0, Wp1, Wl1, Wr1, Wp2, Wout, Wpo);

    fill_csr_kernel<<<nb, 256, 0, stream>>>(gtail, gbuf, cnt4, csr, N);

    int gb = (N + 63) / 64;          // fused: 64 nodes/block (4 waves x 16)
    fused_l1_kernel<<<gb, 256, 0, stream>>>(xb, cnt4, csr, Wp1, b0, h0b, N);
    fused_l2_kernel<<<gb, 256, 0, stream>>>(h0b, cnt4, csr, Wp2, b1,
                                            Wpo, bout, (float*)d_out, N);
}

// Round 5
// 187.045 us; speedup vs baseline: 1.6077x; 1.6077x over previous
//
#include <hip/hip_runtime.h>

// GraphSAGE: 2x SAGEConv(mean) + Linear + softmax.
// Pipeline (5 dispatches): memset(gtail) ->
//   bucket_prep (phase-A LDS bucket-sort of edges | cvt x->bf16 | pack W frags)
//   -> fill_csr (per-bucket CSR build, 2-pass, neighbor lists SORTED BY SRC)
//   -> fused_l1 (gather-mean into LDS + dual MFMA GEMM + relu -> h0 bf16)
//   -> fused_l2 (gather-mean + dual GEMM + relu -> LDS + out-proj + softmax).
//
// R3/R4 post-mortem (both phasing attempts REVERTED in the gather):
//   R3 (column slices): FETCH 115MB but 64B granules -> 2TB/s fill path, 64us.
//   R4 (src-range segments): FETCH 60.5MB (cache win!) but per-range segments
//   ~4 edges -> MLP collapse (VALUBusy 13%, 0.6TB/s), 102us.
// Lesson: this gather is MLP/latency-limited, not hit-rate-limited. The R2
// structure (full 256B uint4 row loads, 8 in flight, clamped dense batches)
// is the efficient regime (~43us/kernel). This round restores it EXACTLY and
// keeps only the free parts of the experiments:
//   - csr neighbor lists are src-sorted (2-pass fill_csr): identical gather
//     code over a permuted list -> zero gather-side cost, passive L2 phase
//     coherence as upside (all quarter-waves sweep src ranges in order).
//   - fused_l1 h0 store goes through the LDS tile -> 256B coalesced rows.
//
// CSR build: bucket = dst>>8 (256-node ranges). Phase A: per-block LDS
// histogram + scan + ~196 global atomics reserving per-(XCD,bucket) segments
// (b&7 XCD heuristic -> single-XCD lines), LDS-sorted dump. Phase B: one
// block per bucket, two passes: count per (node,src-range) -> prefix ->
// LDS-atomic range-grouped placement, coalesced 32KB tile dump + capped cnt.
//
// Dual GEMM as one K=256 MFMA GEMM: A_cat=[agg|root] bf16, W_cat=[Wl;Wr] packed.
// mfma_f32_16x16x32_bf16: A[m=lane&15][k=(lane>>4)*8+j]; B[k][n=lane&15];
// C: col=lane&15, row=(lane>>4)*4+reg (m89/m91-verified layouts).
// Zero barriers in the fused kernels (wave-private LDS tiles, DS wave-ordered).

#define CAP 64
#define NBK 256      // bucket table stride (max buckets; N<=65536)
#define EPB 2048     // edges per phase-A block (8 per thread)
#define BCAP8 768    // per-(XCD,bucket) segment capacity (mean ~510, ~11 sigma)
#define ASTR 136     // LDS A-tile row stride in ushorts (272B = 17x16B)
#define NR 4         // src ranges for passive L2 phasing (sort key only)
#define RSH 14       // range = src >> 14

typedef __attribute__((ext_vector_type(8))) short bf16x8;
typedef __attribute__((ext_vector_type(4))) float f32x4;

__device__ __forceinline__ unsigned short bf16_rtne(float f) {
    unsigned u = __float_as_uint(f);
    u += 0x7FFFu + ((u >> 16) & 1u);
    return (unsigned short)(u >> 16);
}

__device__ __forceinline__ unsigned pack2(float lo, float hi) {
    return (unsigned)bf16_rtne(lo) | ((unsigned)bf16_rtne(hi) << 16);
}

__device__ __forceinline__ void pack_w_body(const float* __restrict__ Wl,
                                            const float* __restrict__ Wr,
                                            unsigned short* __restrict__ Wp, int i) {
    int j = i & 7;
    int l = (i >> 3) & 63;
    int ntile = (i >> 9) & 7;
    int kstep = i >> 12;
    int k = kstep * 32 + (l >> 4) * 8 + j;
    int n = ntile * 16 + (l & 15);
    float v = (k < 128) ? Wl[k * 128 + n] : Wr[(k - 128) * 128 + n];
    Wp[i] = bf16_rtne(v);
}

// Fused dispatch 1: [phase-A bucket scatter | cvt x->bf16 | pack Wp1/Wp2/Wpo].
__global__ __launch_bounds__(256) void bucket_prep_kernel(
        const int* __restrict__ src, const int* __restrict__ dst,
        unsigned int* __restrict__ gtail, unsigned int* __restrict__ gbuf,
        int E, int aBlocks,
        const float* __restrict__ x, unsigned short* __restrict__ xb, int n4, int cvtBlocks,
        const float* __restrict__ Wl0, const float* __restrict__ Wr0,
        unsigned short* __restrict__ Wp1,
        const float* __restrict__ Wl1, const float* __restrict__ Wr1,
        unsigned short* __restrict__ Wp2,
        const float* __restrict__ Wout, unsigned short* __restrict__ Wpo) {
    int b = blockIdx.x;
    if (b < aBlocks) {
        __shared__ unsigned int hist[NBK];
        __shared__ unsigned int pref[NBK + 1];
        __shared__ int baseS[NBK];
        __shared__ unsigned int scat[EPB];
        __shared__ unsigned char scatb[EPB];
        int tid = (int)threadIdx.x;
        int xcd = b & 7;   // XCD heuristic: same (b&7) -> same XCD L2 for segment writes
        hist[tid] = 0u;
        __syncthreads();

        int e0 = b * EPB + tid * 8;
        int dd[8], ss[8], bb[8];
        unsigned rr[8];
        bool vld[8];
        if (e0 + 7 < E) {
            int4 d0 = *(const int4*)(dst + e0);
            int4 d1 = *(const int4*)(dst + e0 + 4);
            int4 s0 = *(const int4*)(src + e0);
            int4 s1 = *(const int4*)(src + e0 + 4);
            dd[0] = d0.x; dd[1] = d0.y; dd[2] = d0.z; dd[3] = d0.w;
            dd[4] = d1.x; dd[5] = d1.y; dd[6] = d1.z; dd[7] = d1.w;
            ss[0] = s0.x; ss[1] = s0.y; ss[2] = s0.z; ss[3] = s0.w;
            ss[4] = s1.x; ss[5] = s1.y; ss[6] = s1.z; ss[7] = s1.w;
#pragma unroll
            for (int u = 0; u < 8; ++u) vld[u] = true;
        } else {
#pragma unroll
            for (int u = 0; u < 8; ++u) {
                int e = e0 + u;
                vld[u] = (e < E);
                dd[u] = vld[u] ? dst[e] : 0;
                ss[u] = vld[u] ? src[e] : 0;
            }
        }
#pragma unroll
        for (int u = 0; u < 8; ++u) {
            bb[u] = dd[u] >> 8;
            rr[u] = vld[u] ? atomicAdd(&hist[bb[u]], 1u) : 0u;
        }
        __syncthreads();
        // exclusive prefix over hist: pref[i] = sum hist[0..i-1] (Hillis-Steele)
        pref[tid + 1] = hist[tid];
        if (tid == 0) pref[0] = 0u;
        __syncthreads();
        for (int off = 1; off < NBK; off <<= 1) {
            unsigned add = (tid + 1 > off) ? pref[tid + 1 - off] : 0u;
            __syncthreads();
            pref[tid + 1] += add;
            __syncthreads();
        }
        // reserve per-(XCD,bucket) segment space: ~196 atomics per block
        {
            unsigned h = hist[tid];
            unsigned gb0 = (h != 0u) ? atomicAdd(&gtail[xcd * NBK + tid], h) : 0u;
            baseS[tid] = (int)((unsigned)(xcd * NBK + tid) * BCAP8 + gb0) - (int)pref[tid];
        }
        __syncthreads();
        // local bucket-sort into LDS
#pragma unroll
        for (int u = 0; u < 8; ++u) {
            if (vld[u]) {
                unsigned idx = pref[bb[u]] + rr[u];
                scat[idx] = ((unsigned)dd[u] << 16) | (unsigned)(ss[u] & 0xFFFF);
                scatb[idx] = (unsigned char)bb[u];
            }
        }
        __syncthreads();
        // dump: contiguous run per bucket -> coalesced-ish, single-XCD lines
        unsigned tot = pref[NBK];
        for (unsigned i = (unsigned)tid; i < tot; i += 256u) {
            int bk = (int)scatb[i];
            int gi = baseS[bk] + (int)i;
            unsigned segBase = (unsigned)(xcd * NBK + bk) * BCAP8;
            if ((unsigned)gi - segBase < BCAP8) gbuf[gi] = scat[i];
        }
    } else if (b < aBlocks + cvtBlocks) {
        int i = (b - aBlocks) * 256 + (int)threadIdx.x;
        if (i < n4) {
            float4 v = ((const float4*)x)[i];
            ushort4 o;
            o.x = bf16_rtne(v.x); o.y = bf16_rtne(v.y);
            o.z = bf16_rtne(v.z); o.w = bf16_rtne(v.w);
            ((ushort4*)xb)[i] = o;
        }
    } else if (b < aBlocks + cvtBlocks + 128) {
        pack_w_body(Wl0, Wr0, Wp1, (b - aBlocks - cvtBlocks) * 256 + (int)threadIdx.x);
    } else if (b < aBlocks + cvtBlocks + 256) {
        pack_w_body(Wl1, Wr1, Wp2, (b - aBlocks - cvtBlocks - 128) * 256 + (int)threadIdx.x);
    } else {
        int i = (b - aBlocks - cvtBlocks - 256) * 256 + (int)threadIdx.x;   // 32 blocks
        int j = i & 7;
        int l = (i >> 3) & 63;
        int nt = (i >> 9) & 3;
        int ks = i >> 11;
        int k = ks * 32 + (l >> 4) * 8 + j;
        int n = nt * 16 + (l & 15);
        Wpo[i] = bf16_rtne(Wout[k * 64 + n]);
    }
}

// Phase B: one block per 256-node bucket, two passes over its 8 XCD segments.
// Pass 1 counts per (node, src-range); per-node prefix -> range-sorted
// placement offsets. Pass 2 places edges grouped by src range via LDS atomics
// (gather code is order-agnostic; sorting gives passive L2 phase coherence).
// Coalesced 32KB csr tile dump + capped cnt write. No global atomics.
__global__ __launch_bounds__(256) void fill_csr_kernel(
        const unsigned int* __restrict__ gtail, const unsigned int* __restrict__ gbuf,
        int* __restrict__ cnt, unsigned short* __restrict__ csr, int N) {
    __shared__ unsigned int cntR[256 * NR];       // 4 KB
    __shared__ unsigned int offR[256 * NR];       // 4 KB
    __shared__ unsigned short stage[256 * CAP];   // 32 KB; garbage beyond deg never read
    int b = blockIdx.x;
    int tid = (int)threadIdx.x;
#pragma unroll
    for (int r = 0; r < NR; ++r) cntR[r * 256 + tid] = 0u;
    __syncthreads();
    // pass 1: count per (node, range)
#pragma unroll 1
    for (int xcd = 0; xcd < 8; ++xcd) {
        unsigned nE = gtail[xcd * NBK + b];
        if (nE > BCAP8) nE = BCAP8;
        const unsigned int* g = gbuf + (size_t)(xcd * NBK + b) * BCAP8;
        for (unsigned i = (unsigned)tid; i < nE; i += 256u) {
            unsigned pk = g[i];
            int dl = (int)((pk >> 16) & 255u);
            int rg = (int)((pk & 0xFFFFu) >> RSH);
            atomicAdd(&cntR[dl * NR + rg], 1u);
        }
    }
    __syncthreads();
    // per-node range offsets + capped total; reset counters for pass 2
    {
        unsigned c0 = cntR[tid * NR + 0], c1 = cntR[tid * NR + 1];
        unsigned c2 = cntR[tid * NR + 2], c3 = cntR[tid * NR + 3];
        offR[tid * NR + 0] = 0u;
        offR[tid * NR + 1] = c0;
        offR[tid * NR + 2] = c0 + c1;
        offR[tid * NR + 3] = c0 + c1 + c2;
        int node = b * 256 + tid;
        if (node < N) cnt[node] = min((int)(c0 + c1 + c2 + c3), CAP);
        cntR[tid * NR + 0] = 0u; cntR[tid * NR + 1] = 0u;
        cntR[tid * NR + 2] = 0u; cntR[tid * NR + 3] = 0u;
    }
    __syncthreads();
    // pass 2: place (src-range-grouped within each node's CAP row)
#pragma unroll 1
    for (int xcd = 0; xcd < 8; ++xcd) {
        unsigned nE = gtail[xcd * NBK + b];
        if (nE > BCAP8) nE = BCAP8;
        const unsigned int* g = gbuf + (size_t)(xcd * NBK + b) * BCAP8;
        for (unsigned i = (unsigned)tid; i < nE; i += 256u) {
            unsigned pk = g[i];
            int dl = (int)((pk >> 16) & 255u);
            int rg = (int)((pk & 0xFFFFu) >> RSH);
            unsigned p = atomicAdd(&cntR[dl * NR + rg], 1u) + offR[dl * NR + rg];
            if (p < CAP) stage[dl * CAP + p] = (unsigned short)(pk & 0xFFFFu);
        }
    }
    __syncthreads();
    const uint4* s4 = (const uint4*)stage;
    uint4* g4 = (uint4*)(csr + (size_t)b * (256 * CAP));
    for (int i = tid; i < (256 * CAP) / 8; i += 256) g4[i] = s4[i];
}

// Per-wave gather+mean into the wave's LDS A-tile (R2 structure, verbatim:
// the MLP-efficient regime). Quarter-wave (16 lanes x uint4 = one 256B row
// per instr) per node, 8 rows in flight, clamped dense batches over the FULL
// (src-sorted) neighbor list. Per-column accumulation order is a permutation
// of previous rounds (f32 sum, tol 1e-3: safe).
__device__ __forceinline__ void gather_mean_lds(
        const uint4* __restrict__ h4,          // bf16 table, one row = 16 uint4
        const int* __restrict__ cnt,
        const unsigned short* __restrict__ csr, unsigned short* __restrict__ sAw,
        int m0, int lane, int N) {
    int qw = lane >> 4;      // quarter-wave 0..3
    int ql = lane & 15;
#pragma unroll 1
    for (int i = 0; i < 4; ++i) {
        int nl = qw * 4 + i;
        int node = m0 + nl;
        int deg = (node < N) ? min(cnt[node], CAP) : 0;
        int s0 = node * CAP;
        int s1 = s0 + deg;
        float a[8];
#pragma unroll
        for (int u = 0; u < 8; ++u) a[u] = 0.f;
        for (int base = 0; base < deg; base += 16) {
            int nc = min(16, deg - base);
            int e = min(s0 + base + ql, s1 - 1);
            int idx = csr[e];
            for (int j = 0; j < nc; j += 8) {
                uint4 v[8];
#pragma unroll
                for (int u = 0; u < 8; ++u) {
                    int sidx = __shfl(idx, j + u, 16);
                    v[u] = h4[(size_t)sidx * 16 + ql];
                }
#pragma unroll
                for (int u = 0; u < 8; ++u) {
                    bool ok = (j + u < nc);
                    unsigned w0 = ok ? v[u].x : 0u;
                    unsigned w1 = ok ? v[u].y : 0u;
                    unsigned w2 = ok ? v[u].z : 0u;
                    unsigned w3 = ok ? v[u].w : 0u;
                    a[0] += __uint_as_float(w0 << 16);
                    a[1] += __uint_as_float(w0 & 0xFFFF0000u);
                    a[2] += __uint_as_float(w1 << 16);
                    a[3] += __uint_as_float(w1 & 0xFFFF0000u);
                    a[4] += __uint_as_float(w2 << 16);
                    a[5] += __uint_as_float(w2 & 0xFFFF0000u);
                    a[6] += __uint_as_float(w3 << 16);
                    a[7] += __uint_as_float(w3 & 0xFFFF0000u);
                }
            }
        }
        float inv = 1.0f / (float)max(deg, 1);
        uint4 o;
        o.x = pack2(a[0] * inv, a[1] * inv);
        o.y = pack2(a[2] * inv, a[3] * inv);
        o.z = pack2(a[4] * inv, a[5] * inv);
        o.w = pack2(a[6] * inv, a[7] * inv);
        *(uint4*)(sAw + nl * ASTR + ql * 8) = o;   // 272B row -> bank-floor reads
    }
}

// MFMA core: wave computes 16 nodes x 128 cols, K=256 ([aggLDS|rootGlobal]).
__device__ __forceinline__ void mfma_dual_gemm_lds(
        const unsigned short* __restrict__ sAw, const unsigned short* __restrict__ rootb,
        const unsigned short* __restrict__ Wp, int rowc, int quad, int c, int lane,
        f32x4 acc[8]) {
#pragma unroll
    for (int t = 0; t < 8; ++t) acc[t] = (f32x4){0.f, 0.f, 0.f, 0.f};
    for (int ks = 0; ks < 8; ++ks) {
        bf16x8 a;
        if (ks < 4) a = *(const bf16x8*)(sAw + c * ASTR + ks * 32 + quad * 8);
        else        a = *(const bf16x8*)(rootb + (size_t)rowc * 128 + (ks & 3) * 32 + quad * 8);
#pragma unroll
        for (int t = 0; t < 8; ++t) {
            bf16x8 bf = *(const bf16x8*)(Wp + ((size_t)(ks * 8 + t) * 64 + lane) * 8);
            acc[t] = __builtin_amdgcn_mfma_f32_16x16x32_bf16(a, bf, acc[t], 0, 0, 0);
        }
    }
}

// Layer 1: h0 = relu(mean_agg(x)@Wl + x@Wr + b) -> bf16 store.
// Gather, GEMM, and the h0 repack all stay on the wave's own LDS tile:
// no barriers (DS ops wave-ordered). h0 stored as coalesced 256B rows.
__global__ __launch_bounds__(256) void fused_l1_kernel(
        const unsigned short* __restrict__ hb, const int* __restrict__ cnt,
        const unsigned short* __restrict__ csr, const unsigned short* __restrict__ Wp,
        const float* __restrict__ b, unsigned short* __restrict__ houtb, int N) {
    __shared__ unsigned short sA[4][16 * ASTR];   // 17.4 KB
    int lane = threadIdx.x & 63;
    int wv = threadIdx.x >> 6;
    int m0 = blockIdx.x * 64 + wv * 16;
    gather_mean_lds((const uint4*)hb, cnt, csr, &sA[wv][0], m0, lane, N);
    int quad = lane >> 4;
    int c = lane & 15;
    int rowc = min(m0 + c, N - 1);
    f32x4 acc[8];
    mfma_dual_gemm_lds(&sA[wv][0], hb, Wp, rowc, quad, c, lane, acc);
    // relu+bias -> sA (overwrites A-tile; wave-private, DS wave-ordered)
#pragma unroll
    for (int t = 0; t < 8; ++t) {
        int col = t * 16 + c;
        float bias = b[col];
#pragma unroll
        for (int r = 0; r < 4; ++r) {
            sA[wv][(quad * 4 + r) * ASTR + col] = bf16_rtne(fmaxf(acc[t][r] + bias, 0.f));
        }
    }
    // coalesced store: quarter-wave ql covers 16B -> 256B per row per instr
    {
        int qw = lane >> 4, ql = lane & 15;
#pragma unroll
        for (int i = 0; i < 4; ++i) {
            int nl = qw * 4 + i;
            int node = m0 + nl;
            if (node < N) {
                uint4 row = *(const uint4*)(&sA[wv][nl * ASTR + ql * 8]);
                *(uint4*)(houtb + (size_t)node * 128 + ql * 8) = row;
            }
        }
    }
}

// Layer 2 + out-projection + softmax. h1 tile staged back into the same LDS
// A-tile (stride 136 -> conflict-floor reads in the out-proj too). No barriers.
__global__ __launch_bounds__(256) void fused_l2_kernel(
        const unsigned short* __restrict__ hb, const int* __restrict__ cnt,
        const unsigned short* __restrict__ csr, const unsigned short* __restrict__ Wp,
        const float* __restrict__ b,
        const unsigned short* __restrict__ Wpo, const float* __restrict__ bout,
        float* __restrict__ out, int N) {
    __shared__ unsigned short sA[4][16 * ASTR];   // 17.4 KB, reused for h1 tile
    int lane = threadIdx.x & 63;
    int wv = threadIdx.x >> 6;
    int m0 = blockIdx.x * 64 + wv * 16;
    gather_mean_lds((const uint4*)hb, cnt, csr, &sA[wv][0], m0, lane, N);
    int quad = lane >> 4;
    int c = lane & 15;
    int rowc = min(m0 + c, N - 1);
    f32x4 acc[8];
    mfma_dual_gemm_lds(&sA[wv][0], hb, Wp, rowc, quad, c, lane, acc);
    // relu -> h1 tile in LDS (wave-private; DS ops are wave-ordered, no barrier)
#pragma unroll
    for (int t = 0; t < 8; ++t) {
        int col = t * 16 + c;
        float bias = b[col];
#pragma unroll
        for (int r = 0; r < 4; ++r) {
            sA[wv][(quad * 4 + r) * ASTR + col] = bf16_rtne(fmaxf(acc[t][r] + bias, 0.f));
        }
    }

    // out = h1 @ Wout : K=128 (4 ksteps), N=64 (4 ntiles) -> 16 MFMAs.
    f32x4 acc2[4];
#pragma unroll
    for (int nt = 0; nt < 4; ++nt) acc2[nt] = (f32x4){0.f, 0.f, 0.f, 0.f};
#pragma unroll
    for (int ks = 0; ks < 4; ++ks) {
        bf16x8 a = *(const bf16x8*)&sA[wv][c * ASTR + ks * 32 + quad * 8];
#pragma unroll
        for (int nt = 0; nt < 4; ++nt) {
            bf16x8 bf = *(const bf16x8*)(Wpo + ((size_t)(ks * 4 + nt) * 64 + lane) * 8);
            acc2[nt] = __builtin_amdgcn_mfma_f32_16x16x32_bf16(a, bf, acc2[nt], 0, 0, 0);
        }
    }

    // softmax: row m=quad*4+r lives in a 16-lane group x 4 regs (nt).
    float bo[4];
#pragma unroll
    for (int nt = 0; nt < 4; ++nt) bo[nt] = bout[nt * 16 + c];
#pragma unroll
    for (int r = 0; r < 4; ++r) {
        float v[4];
#pragma unroll
        for (int nt = 0; nt < 4; ++nt) v[nt] = acc2[nt][r] + bo[nt];
        float m = fmaxf(fmaxf(v[0], v[1]), fmaxf(v[2], v[3]));
#pragma unroll
        for (int ofs = 1; ofs < 16; ofs <<= 1) m = fmaxf(m, __shfl_xor(m, ofs, 64));
        float e[4];
        float s = 0.f;
#pragma unroll
        for (int nt = 0; nt < 4; ++nt) { e[nt] = __expf(v[nt] - m); s += e[nt]; }
#pragma unroll
        for (int ofs = 1; ofs < 16; ofs <<= 1) s += __shfl_xor(s, ofs, 64);
        float inv = 1.0f / s;
        int node = m0 + quad * 4 + r;
        if (node < N) {
#pragma unroll
            for (int nt = 0; nt < 4; ++nt)
                out[(size_t)node * 64 + nt * 16 + c] = e[nt] * inv;
        }
    }
}

extern "C" void kernel_launch(void* const* d_in, const int* in_sizes, int n_in,
                              void* d_out, int out_size, void* d_ws, size_t ws_size,
                              hipStream_t stream) {
    const float* x    = (const float*)d_in[0];
    const int*   ei   = (const int*)d_in[1];
    const float* Wl0  = (const float*)d_in[2];
    const float* Wr0  = (const float*)d_in[3];
    const float* b0   = (const float*)d_in[4];
    const float* Wl1  = (const float*)d_in[5];
    const float* Wr1  = (const float*)d_in[6];
    const float* b1   = (const float*)d_in[7];
    const float* Wout = (const float*)d_in[8];
    const float* bout = (const float*)d_in[9];

    int N = in_sizes[0] / 128;
    int E = in_sizes[1] / 2;
    const int* src = ei;
    const int* dst = ei + E;
    int nb = (N + 255) >> 8;             // node buckets (256 nodes each)

    char* p = (char*)d_ws;
    auto alloc = [&](size_t bytes) -> char* {
        char* r = p;
        p += (bytes + 255) & ~(size_t)255;
        return r;
    };
    unsigned int*   gtail = (unsigned int*)alloc((size_t)8 * NBK * 4);
    unsigned int*   gbuf  = (unsigned int*)alloc((size_t)8 * NBK * BCAP8 * 4);
    int*            cnt   = (int*)alloc((size_t)N * 4);
    unsigned short* csr   = (unsigned short*)alloc((size_t)nb * 256 * CAP * 2);
    unsigned short* xb    = (unsigned short*)alloc((size_t)N * 128 * 2);
    unsigned short* h0b   = (unsigned short*)alloc((size_t)N * 128 * 2);
    unsigned short* Wp1   = (unsigned short*)alloc((size_t)32768 * 2);
    unsigned short* Wp2   = (unsigned short*)alloc((size_t)32768 * 2);
    unsigned short* Wpo   = (unsigned short*)alloc((size_t)8192 * 2);

    hipMemsetAsync(gtail, 0, (size_t)8 * NBK * 4, stream);

    int n4 = N * 128 / 4;
    int cvtBlocks = (n4 + 255) / 256;
    int aBlocks = (E + EPB - 1) / EPB;
    bucket_prep_kernel<<<aBlocks + cvtBlocks + 256 + 32, 256, 0, stream>>>(
        src, dst, gtail, gbuf, E, aBlocks,
        x, xb, n4, cvtBlocks, Wl0, Wr0, Wp1, Wl1, Wr1, Wp2, Wout, Wpo);

    fill_csr_kernel<<<nb, 256, 0, stream>>>(gtail, gbuf, cnt, csr, N);

    int gb = (N + 63) / 64;          // fused: 64 nodes/block (4 waves x 16)
    fused_l1_kernel<<<gb, 256, 0, stream>>>(xb, cnt, csr, Wp1, b0, h0b, N);
    fused_l2_kernel<<<gb, 256, 0, stream>>>(h0b, cnt, csr, Wp2, b1,
                                            Wpo, bout, (float*)d_out, N);
}